// Round 6
// baseline (263.451 us; speedup 1.0000x reference)
//
#include <hip/hip_runtime.h>
#include <math.h>

#define EN 16
#define TBL_N 1024                       // intervals
#define TBL_XMAX 20.0f
#define TBL_SCALE ((float)TBL_N / TBL_XMAX)
#define TBL_STEP  (TBL_XMAX / (float)TBL_N)
// ws layout (floats): [0..1024] att, [1025..2049] rep, [2050..3074] bor, [3075] del_one
#define WS_ATT 0
#define WS_REP 1025
#define WS_BOR 2050
#define WS_DEL1 3075
#define WS_TOTAL 3076

// Tabulate mono(x) = sum_e w2[e]*exp(-(x*w1[e]+b1[e])) + b2 for att/rep/bor
// on x = i*STEP, i in [0,1024]; plus del(1.0) at WS_DEL1.
extern "C" __global__ void __launch_bounds__(256)
build_tables(const float* __restrict__ rep_w1, const float* __restrict__ rep_b1,
             const float* __restrict__ rep_w2, const float* __restrict__ rep_b2,
             const float* __restrict__ att_w1, const float* __restrict__ att_b1,
             const float* __restrict__ att_w2, const float* __restrict__ att_b2,
             const float* __restrict__ bor_w1, const float* __restrict__ bor_b1,
             const float* __restrict__ bor_w2, const float* __restrict__ bor_b2,
             const float* __restrict__ del_w1, const float* __restrict__ del_b1,
             const float* __restrict__ del_w2, const float* __restrict__ del_b2,
             float* __restrict__ ws)
{
    int gid = blockIdx.x * blockDim.x + threadIdx.x;
    if (gid >= WS_TOTAL) return;

    const float *w1, *b1, *w2, *b2;
    float x;
    if (gid == WS_DEL1) {
        w1 = del_w1; b1 = del_b1; w2 = del_w2; b2 = del_b2; x = 1.0f;
    } else {
        int net = gid / 1025;
        int e = gid - net * 1025;
        x = (float)e * TBL_STEP;
        if (net == 0)      { w1 = att_w1; b1 = att_b1; w2 = att_w2; b2 = att_b2; }
        else if (net == 1) { w1 = rep_w1; b1 = rep_b1; w2 = rep_w2; b2 = rep_b2; }
        else               { w1 = bor_w1; b1 = bor_b1; w2 = bor_w2; b2 = bor_b2; }
    }
    float acc = 0.0f;
#pragma unroll
    for (int e = 0; e < EN; ++e)
        acc = fmaf(__expf(-fmaf(x, w1[e], b1[e])), w2[e], acc);
    ws[gid] = acc + b2[0];
}

__device__ __forceinline__ float tbl_lookup(const float* __restrict__ T, float x) {
    float t = x * TBL_SCALE;
    int i = (int)t;
    i = (i > TBL_N - 1) ? (TBL_N - 1) : i;   // clamp (x<20 in practice)
    float fr = t - (float)i;
    float f0 = T[i], f1 = T[i + 1];
    return fmaf(fr, f1 - f0, f0);
}

// One lane per (agent n, neighbor k); 8 lanes/agent within a wave.
// Hot monos come from LDS lerp tables (err ~2e-4); gates are magnitude-
// independent (|cos| cancels scalar and sign), so table error cannot flip
// a gate and perturbs outputs by ~1e-3 << 0.39 threshold.
extern "C" __global__ void __launch_bounds__(256)
sfm_kernel(const float* __restrict__ ego, const float* __restrict__ nei,
           const float* __restrict__ border, const float* __restrict__ rec,
           const float* __restrict__ p_dest, const float* __restrict__ angle,
           const float* __restrict__ del_w1, const float* __restrict__ del_b1,
           const float* __restrict__ del_w2, const float* __restrict__ del_b2,
           const float* __restrict__ ws,
           float* __restrict__ out, int N)
{
    const int gid = blockIdx.x * blockDim.x + threadIdx.x;
    const int n = gid >> 3;
    const int k = gid & 7;
    const int lane = threadIdx.x & 63;
    const int gbase = lane & ~7;

    // ---- issue per-lane data loads first (latency hides under table copy) ----
    float2 e2 = *(const float2*)(ego + (size_t)n * 16 + 2 * k);      // ego cols [2k,2k+1]
    const float* nb = nei + (size_t)n * 128 + (size_t)k * 16;
    float4 na = *(const float4*)nb;                                   // id,x,y,vx
    float nvyv = nb[4];                                               // vy
    float2 rc = *(const float2*)(rec + (size_t)n * 16 + 2 * k);
    const float ang = angle[0];
    const float p0 = p_dest[0], p1 = p_dest[1];
    const float b0 = border[0], b3 = border[3];
    const float del_one = ws[WS_DEL1];

    // ---- copy tables to LDS (12.3 KB), coalesced ----
    __shared__ float T[WS_TOTAL - 1];   // att|rep|bor
    for (int i = threadIdx.x; i < WS_TOTAL - 1; i += 256)
        T[i] = ws[i];
    __syncthreads();

    // ---- rebuild ego scalars via intra-group shuffles ----
    const float ex = e2.x, ey = e2.y;
    const float px  = __shfl(ey, gbase + 0);   // col1
    const float py  = __shfl(ex, gbase + 1);   // col2
    const float vx  = __shfl(ey, gbase + 1);   // col3
    const float vy  = __shfl(ex, gbase + 2);   // col4
    const float id0 = __shfl(ey, gbase + 3);   // col7
    const float id1 = __shfl(ex, gbase + 4);
    const float id2 = __shfl(ey, gbase + 4);
    const float id3 = __shfl(ex, gbase + 5);
    const float id4 = __shfl(ey, gbase + 5);
    const float id5 = __shfl(ex, gbase + 6);
    const float id6 = __shfl(ey, gbase + 6);
    const float id7 = __shfl(ex, gbase + 7);   // col14

    const float speed = sqrtf(vx * vx + vy * vy);
    const float nid = na.x;
    const float bid = rc.x, bct = rc.y;

    // ---- count: wave-uniform fast path ----
    unsigned long long m1 = __ballot(bid != 0.0f);
    unsigned long long m2 = __ballot(nid == 0.0f);
    float cntk;
    if ((m1 | m2) == 0ull) {
        cntk = 1.0f;     // all bid==0 & all nid!=0 => fin all-false => cnt=1
    } else {
        bool fin = (bid == nid);
#pragma unroll
        for (int t = 1; t < 8; ++t)
            fin = fin || (bid == __shfl_xor(nid, t));
        unsigned long long bal = __ballot(fin);
        unsigned finM = (unsigned)((bal >> gbase) & 0xFFull);
        int popcFin = __popc(finM);
        int jsel = 0, cbits = 0;
#pragma unroll
        for (int j = 0; j < 8; ++j) {
            int bit = (finM >> j) & 1;
            if (bit && cbits == k) jsel = j;
            cbits += bit;
        }
        float bctj = __shfl(bct, gbase + jsel);
        cntk = (k < popcFin) ? (bctj + 1.0f) : 1.0f;
    }

    // idx: neighbor id among ego cols 7..14
    bool match = (nid == id0) || (nid == id1) || (nid == id2) || (nid == id3)
              || (nid == id4) || (nid == id5) || (nid == id6) || (nid == id7);
    const bool idxk = match && (nid != 0.0f);

    float rx = idxk ? (na.y - px) : 0.0f;
    float ry = idxk ? (na.z - py) : 0.0f;
    float rn = sqrtf(rx * rx + ry * ry);
    float rns = idxk ? rn : 1.0f;
    float dx = rx / rns, dy = ry / rns;

    // repulsion input b
    float sxv = na.w * 0.02f, syv = nvyv * 0.02f;
    float ox = rx + sxv, oy = ry + syv;
    float bsum = rn + (ox * ox + oy * oy) - (sxv * sxv + syv * syv);
    float bgate = idxk ? bsum : 1.0f;
    float bb = sqrtf(fmaxf(bgate, 1e-12f)) * 0.5f;

    // ---- table lookups replace the exp chains ----
    float att = tbl_lookup(T + WS_ATT, rn);
    float rep = tbl_lookup(T + WS_REP, bb);

    // del: fast path cnt==1 -> cached del_one; rare general path exact
    float del;
    if (cntk == 1.0f) {
        del = del_one;
    } else {
        float accd = 0.0f;
#pragma unroll
        for (int e = 0; e < EN; ++e)
            accd = fmaf(__expf(-fmaf(cntk, del_w1[e], del_b1[e])), del_w2[e], accd);
        del = accd + del_b2[0];
    }

    float nbx = 0.0f, nby = 0.0f;
    {
        float sa = del * att;
        float fax = idxk ? sa * dx : 0.0f;
        float fay = idxk ? sa * dy : 0.0f;
        float num = vx * fax + vy * fay;
        float fn = sqrtf(fax * fax + fay * fay);
        float den = fmaxf(speed * fn, 1e-8f);
        if (fabsf(num / den) > ang) { nbx += fax; nby += fay; }
    }
    {
        float frx = idxk ? rep * dx : 0.0f;
        float fry = idxk ? rep * dy : 0.0f;
        float num = vx * frx + vy * fry;
        float fn = sqrtf(frx * frx + fry * fry);
        float den = fmaxf(speed * fn, 1e-8f);
        if (fabsf(num / den) > ang) { nbx += frx; nby += fry; }
    }

    // border (y-only): compute on all lanes, select on k<2
    float bory;
    {
        float bsel = (k == 0) ? b0 : b3;
        float rb = py - bsel;
        float rbn = fabsf(rb);
        float mb = tbl_lookup(T + WS_BOR, rbn);
        float fby = mb * (rb / rbn);
        float num = vy * fby;
        float den = fmaxf(speed * fabsf(fby), 1e-8f);
        bory = ((fabsf(num / den) > ang) && (k < 2)) ? fby : 0.0f;
    }

    // xor-butterfly sum over the 8-lane group
#pragma unroll
    for (int m = 1; m < 8; m <<= 1) {
        nbx  += __shfl_xor(nbx,  m);
        nby  += __shfl_xor(nby,  m);
        bory += __shfl_xor(bory, m);
    }

    // destination force (uniform across group)
    float fdx = (p1 * speed - vx) / p0;
    float fdy = (0.0f - vy) / p0;
    float fdex = 0.0f, fdey = 0.0f;
    {
        float num = vx * fdx + vy * fdy;
        float fn = sqrtf(fdx * fdx + fdy * fdy);
        float den = fmaxf(speed * fn, 1e-8f);
        if (fabsf(num / den) > ang) { fdex = fdx; fdey = fdy; }
    }

    if (n >= N) return;
    // output (N,3,2): lanes 0..5 write one float each
    float wv = (k == 0) ? fdex
             : (k == 1) ? fdey
             : (k == 2) ? nbx
             : (k == 3) ? nby
             : (k == 4) ? 0.0f
             : bory;
    if (k < 6) out[(size_t)n * 6 + k] = wv;
}

extern "C" void kernel_launch(void* const* d_in, const int* in_sizes, int n_in,
                              void* d_out, int out_size, void* d_ws, size_t ws_size,
                              hipStream_t stream) {
    const float* ego    = (const float*)d_in[0];
    const float* nei    = (const float*)d_in[1];
    const float* border = (const float*)d_in[2];
    const float* rec    = (const float*)d_in[3];
    const float* p_dest = (const float*)d_in[4];
    const float* angle  = (const float*)d_in[5];
    const float* rep_w1 = (const float*)d_in[6];
    const float* rep_b1 = (const float*)d_in[7];
    const float* rep_w2 = (const float*)d_in[8];
    const float* rep_b2 = (const float*)d_in[9];
    const float* att_w1 = (const float*)d_in[10];
    const float* att_b1 = (const float*)d_in[11];
    const float* att_w2 = (const float*)d_in[12];
    const float* att_b2 = (const float*)d_in[13];
    const float* bor_w1 = (const float*)d_in[14];
    const float* bor_b1 = (const float*)d_in[15];
    const float* bor_w2 = (const float*)d_in[16];
    const float* bor_b2 = (const float*)d_in[17];
    const float* del_w1 = (const float*)d_in[18];
    const float* del_b1 = (const float*)d_in[19];
    const float* del_w2 = (const float*)d_in[20];
    const float* del_b2 = (const float*)d_in[21];
    float* out = (float*)d_out;
    float* ws  = (float*)d_ws;

    int N = in_sizes[0] / 16;

    build_tables<<<dim3((WS_TOTAL + 255) / 256), 256, 0, stream>>>(
        rep_w1, rep_b1, rep_w2, rep_b2,
        att_w1, att_b1, att_w2, att_b2,
        bor_w1, bor_b1, bor_w2, bor_b2,
        del_w1, del_b1, del_w2, del_b2, ws);

    long long threads = (long long)N * 8;
    dim3 grid((unsigned)((threads + 255) / 256));
    sfm_kernel<<<grid, 256, 0, stream>>>(
        ego, nei, border, rec, p_dest, angle,
        del_w1, del_b1, del_w2, del_b2,
        ws, out, N);
}